// Round 9
// baseline (97.732 us; speedup 1.0000x reference)
//
#include <hip/hip_runtime.h>
#include <hip/hip_bf16.h>
#include <stdint.h>

// Problem constants: B=1, S=2048, H=1024, I=512, E=16, K=4
#define HH 1024
#define II 512
#define EE 16
#define TT 2048
#define KTOP 4
#define PP (TT * KTOP)      // 8192 routed pairs
#define MAXROWS 12288       // padded row capacity

typedef unsigned short u16;
typedef unsigned int u32;
typedef __attribute__((ext_vector_type(8))) short short8;       // bf16 MFMA A/B frag
typedef __attribute__((ext_vector_type(4))) float f32x4;        // MFMA C/D frag
typedef __attribute__((ext_vector_type(4))) unsigned short u16x4;
typedef __attribute__((ext_vector_type(8))) unsigned short u16x8;

__device__ __forceinline__ u16 f2bf(float f) {  // fp32 -> bf16 RNE (manual)
  union { float f; unsigned u; } v; v.f = f;
  unsigned r = v.u + 0x7fffu + ((v.u >> 16) & 1u);
  return (u16)(r >> 16);
}
__device__ __forceinline__ float bf2f(u16 b) {
  union { unsigned u; float f; } v; v.u = ((unsigned)b) << 16; return v.f;
}
__device__ __forceinline__ u16 f2bf_hw(float f) {  // RNE via HW cvt
  __hip_bfloat16 h = __float2bfloat16(f);
  union { __hip_bfloat16 h; u16 s; } v; v.h = h; return v.s;
}

// Direct global->LDS DMA, 16B per lane; dest wave-uniform base + lane*16.
__device__ __forceinline__ void gld16(const u16* g, u16* l) {
  __builtin_amdgcn_global_load_lds(
      (const __attribute__((address_space(1))) unsigned int*)g,
      (__attribute__((address_space(3))) unsigned int*)l, 16, 0, 0);
}

// ================= prep: route (block 0, 16 waves) + x cvt (blocks 1..128) ==========
__global__ __launch_bounds__(1024) void prep_small(
    const float* __restrict__ x, const int* __restrict__ tidx,
    const float* __restrict__ tw,
    u16* __restrict__ xb,
    int* __restrict__ perm, float* __restrict__ wt, int* __restrict__ rowof,
    int* __restrict__ tile_e, int* __restrict__ tile_r,
    int* __restrict__ ntiles) {
  __shared__ int s_e[PP];          // bits0-3: e, bit4: valid, bits16+: rank
  __shared__ int whist[16][16];
  __shared__ int wbase[16][16];
  __shared__ int pad_lo[EE], pad_hi[EE];

  const int bid = blockIdx.x;
  const int tid = threadIdx.x;

  if (bid == 0) {
    const int lane = tid & 63;
    const int wv = tid >> 6;

#pragma unroll
    for (int i = 0; i < 2; i++) {
      const int t = tid + i * 1024;
      const int4 v = ((const int4*)tidx)[t];
      const bool v0 = (v.x != v.y) && (v.x != v.z) && (v.x != v.w);
      const bool v1 = (v.y != v.z) && (v.y != v.w);
      const bool v2 = (v.z != v.w);
      s_e[t * 4 + 0] = v.x | (v0 ? 16 : 0);
      s_e[t * 4 + 1] = v.y | (v1 ? 16 : 0);
      s_e[t * 4 + 2] = v.z | (v2 ? 16 : 0);
      s_e[t * 4 + 3] = v.w | 16;
    }
    __syncthreads();

    int h0, h1, h2, h3, h4, h5, h6, h7, h8, h9, h10, h11, h12, h13, h14, h15;
    h0=h1=h2=h3=h4=h5=h6=h7=h8=h9=h10=h11=h12=h13=h14=h15=0;
    const unsigned long long ltm = (1ull << lane) - 1ull;
    for (int c = 0; c < 8; c++) {
      const int p = (wv << 9) + (c << 6) + lane;
      const int se = s_e[p];
      const int e = se & 15;
      const bool valid = (se & 16) != 0;
      int rank = 0;
#define RANK_STEP(J, HJ)                                            \
      {                                                             \
        unsigned long long m = __ballot(valid && (e == J));         \
        if (valid && (e == J)) rank = HJ + __popcll(m & ltm);       \
        HJ += __popcll(m);                                          \
      }
      RANK_STEP(0, h0)  RANK_STEP(1, h1)  RANK_STEP(2, h2)  RANK_STEP(3, h3)
      RANK_STEP(4, h4)  RANK_STEP(5, h5)  RANK_STEP(6, h6)  RANK_STEP(7, h7)
      RANK_STEP(8, h8)  RANK_STEP(9, h9)  RANK_STEP(10, h10) RANK_STEP(11, h11)
      RANK_STEP(12, h12) RANK_STEP(13, h13) RANK_STEP(14, h14) RANK_STEP(15, h15)
#undef RANK_STEP
      if (valid) s_e[p] = se | (rank << 16);
    }
    if (lane == 0) {
      whist[wv][0] = h0;   whist[wv][1] = h1;   whist[wv][2] = h2;   whist[wv][3] = h3;
      whist[wv][4] = h4;   whist[wv][5] = h5;   whist[wv][6] = h6;   whist[wv][7] = h7;
      whist[wv][8] = h8;   whist[wv][9] = h9;   whist[wv][10] = h10; whist[wv][11] = h11;
      whist[wv][12] = h12; whist[wv][13] = h13; whist[wv][14] = h14; whist[wv][15] = h15;
    }
    __syncthreads();

    if (tid == 0) {
      int off = 0, nt = 0;
      for (int j = 0; j < EE; j++) {
        int tot = 0;
        for (int w = 0; w < 16; w++) { wbase[w][j] = off + tot; tot += whist[w][j]; }
        const int cap = (tot + 127) & ~127;
        pad_lo[j] = off + tot;
        pad_hi[j] = off + cap;
        for (int m0 = 0; m0 < cap; m0 += 128) { tile_e[nt] = j; tile_r[nt] = off + m0; nt++; }
        off += cap;
      }
      *ntiles = nt;
    }
    __syncthreads();

#pragma unroll
    for (int i = 0; i < 8; i++) {
      const int p = i * 1024 + tid;
      const int se = s_e[p];
      int pos = -1;
      if (se & 16) {
        const int e = se & 15;
        const int r = se >> 16;
        pos = wbase[p >> 9][e] + r;
        perm[pos] = p >> 2;
        wt[pos] = tw[p];
      }
      rowof[p] = pos;
    }
    for (int j = 0; j < EE; j++) {
      const int lo = pad_lo[j], hi = pad_hi[j];
      for (int i = lo + tid; i < hi; i += 1024) {
        perm[i] = 0;          // pad: token 0 with weight 0 contributes nothing
        wt[i] = 0.f;
      }
    }
    return;
  }

  // ---- x fp32 -> bf16, 16 elems/thread ----
  const int base = ((bid - 1) * 1024 + tid) * 16;
  f32x4 v0 = *(const f32x4*)(x + base);
  f32x4 v1 = *(const f32x4*)(x + base + 4);
  f32x4 v2 = *(const f32x4*)(x + base + 8);
  f32x4 v3 = *(const f32x4*)(x + base + 12);
  u16x8 o0 = { f2bf(v0[0]), f2bf(v0[1]), f2bf(v0[2]), f2bf(v0[3]),
               f2bf(v1[0]), f2bf(v1[1]), f2bf(v1[2]), f2bf(v1[3]) };
  u16x8 o1 = { f2bf(v2[0]), f2bf(v2[1]), f2bf(v2[2]), f2bf(v2[3]),
               f2bf(v3[0]), f2bf(v3[1]), f2bf(v3[2]), f2bf(v3[3]) };
  *(u16x8*)(xb + base) = o0;
  *(u16x8*)(xb + base + 8) = o1;
}

// ===================== GEMM1: ACT = silu(x@Wg) * (x@Wu) * gate_w =====================
// Tile 128(M) x 64(N), BK=64, 4 waves 2x2 (each 64M x 32N).
// A: gld16 -> LDS (XOR swizzle on global source chunk).
// B: COALESCED dwordx4 over n (4x256B segments/instr) -> regs -> bf16 k-pair pack
//    -> ds_write_b32 into [n][kp] LDS with chunk XOR ((n>>1)&7). One barrier/tile.
__global__ __launch_bounds__(256) void gemm1_kernel(
    const u16* __restrict__ xb, const float* __restrict__ wg,
    const float* __restrict__ wu,
    const int* __restrict__ perm, const float* __restrict__ wt,
    const int* __restrict__ tile_e, const int* __restrict__ tile_r,
    const int* __restrict__ ntiles, u16* __restrict__ ACT) {
  const int tileid = blockIdx.y;
  if (tileid >= *ntiles) return;
  const int e = tile_e[tileid];
  const int row0 = tile_r[tileid];
  const int n0 = blockIdx.x * 64;

  __shared__ __align__(16) u16 As[2][128 * 64];       // 32 KB (A dbuf)
  __shared__ __align__(16) u32 Bs[2][2][64 * 32];     // 32 KB [buf][mat][n*32+kp]

  const int tid = threadIdx.x;
  const int lane = tid & 63;
  const int wid = tid >> 6;
  const int wm = wid >> 1, wn = wid & 1;
  const int fr = lane & 15, fq = lane >> 4;

  const int lrow = lane >> 3;
  const int sc8 = ((lane & 7) ^ lrow) * 8;     // A: pre-swizzled source chunk

  const u16* gA[4];
#pragma unroll
  for (int j = 0; j < 4; j++)
    gA[j] = xb + (size_t)perm[row0 + j * 32 + wid * 8 + lrow] * HH + sc8;

  // B staging coords: wave owns k-pairs [wid*8, wid*8+8); lane covers (kp, 4n)
  const int n4 = fr * 4;                        // 4 consecutive n
  const int kpl = wid * 8 + fq;                 // +r*4 per round
  const float* gBm[2];
  gBm[0] = wg + (size_t)e * HH * II + n0 + n4;
  gBm[1] = wu + (size_t)e * HH * II + n0 + n4;

  f32x4 accg[4][2], accu[4][2];
  const f32x4 vz = {0.f, 0.f, 0.f, 0.f};
#pragma unroll
  for (int m = 0; m < 4; m++)
#pragma unroll
    for (int n = 0; n < 2; n++) { accg[m][n] = vz; accu[m][n] = vz; }

  f32x4 bl[2][2], bh[2][2];    // [mat][round] lo/hi k of the pair

#define G1_LOADB(K0)                                                      \
  _Pragma("unroll")                                                       \
  for (int mt = 0; mt < 2; mt++)                                          \
    _Pragma("unroll")                                                     \
    for (int r = 0; r < 2; r++) {                                         \
      const float* p = gBm[mt] + (size_t)((K0) + 2 * (kpl + r * 4)) * II; \
      bl[mt][r] = *(const f32x4*)p;                                       \
      bh[mt][r] = *(const f32x4*)(p + II);                                \
    }

#define G1_WRITEB(BP)                                                     \
  _Pragma("unroll")                                                       \
  for (int mt = 0; mt < 2; mt++)                                          \
    _Pragma("unroll")                                                     \
    for (int r = 0; r < 2; r++)                                           \
      _Pragma("unroll")                                                   \
      for (int i = 0; i < 4; i++) {                                       \
        const int n = n4 + i;                                             \
        const u32 pk = (u32)f2bf_hw(bl[mt][r][i]) |                       \
                       ((u32)f2bf_hw(bh[mt][r][i]) << 16);                \
        (BP)[mt * 2048 + n * 32 +                                         \
             (((wid * 2 + r) ^ ((n >> 1) & 7)) * 4 | fq)] = pk;           \
      }

#define G1_STAGEA(DST, K0)                                                \
  _Pragma("unroll")                                                       \
  for (int j = 0; j < 4; j++) gld16(gA[j] + (K0), (DST) + (j * 4 + wid) * 512);

#define G1_COMPUTE(ASRC, BP)                                              \
  _Pragma("unroll")                                                       \
  for (int ks = 0; ks < 2; ks++) {                                        \
    short8 af[4];                                                         \
    _Pragma("unroll")                                                     \
    for (int m = 0; m < 4; m++) {                                         \
      const int rr = wm * 64 + m * 16 + fr;                               \
      af[m] = *(const short8*)&(ASRC)[rr * 64 + (((ks * 4 + fq) ^ (rr & 7)) * 8)]; \
    }                                                                     \
    _Pragma("unroll")                                                     \
    for (int nn = 0; nn < 2; nn++) {                                      \
      const int n = wn * 32 + nn * 16 + fr;                               \
      const int bo = n * 32 + (((ks * 4 + fq) ^ ((n >> 1) & 7)) * 4);     \
      const short8 bg = *(const short8*)&(BP)[bo];                        \
      const short8 bu = *(const short8*)&(BP)[2048 + bo];                 \
      _Pragma("unroll")                                                   \
      for (int m = 0; m < 4; m++) {                                       \
        accg[m][nn] = __builtin_amdgcn_mfma_f32_16x16x32_bf16(af[m], bg, accg[m][nn], 0, 0, 0); \
        accu[m][nn] = __builtin_amdgcn_mfma_f32_16x16x32_bf16(af[m], bu, accu[m][nn], 0, 0, 0); \
      }                                                                   \
    }                                                                     \
  }

  u16* Acur = &As[0][0]; u16* Anxt = &As[1][0];
  u32* Bcur = &Bs[0][0][0]; u32* Bnxt = &Bs[1][0][0];

  // prologue: tile 0
  G1_LOADB(0)
  G1_STAGEA(Acur, 0)
  G1_WRITEB(Bcur)
  __syncthreads();

  for (int t = 0; t < 16; t++) {
    if (t < 15) {
      G1_LOADB((t + 1) * 64)
      G1_STAGEA(Anxt, (t + 1) * 64)
    }
    G1_COMPUTE(Acur, Bcur)
    if (t < 15) G1_WRITEB(Bnxt)
    __syncthreads();
    u16* ta = Acur; Acur = Anxt; Anxt = ta;
    u32* tb = Bcur; Bcur = Bnxt; Bnxt = tb;
  }

  // C/D: col = lane&15, row = fq*4 + jj within each 16-row m-frag
#pragma unroll
  for (int m = 0; m < 4; m++)
#pragma unroll
    for (int jj = 0; jj < 4; jj++) {
      const int rloc = wm * 64 + m * 16 + fq * 4 + jj;
      const float w = wt[row0 + rloc];
#pragma unroll
      for (int nn = 0; nn < 2; nn++) {
        const float g = accg[m][nn][jj];
        const float u = accu[m][nn][jj];
        const float s = g / (1.f + __expf(-g));   // silu
        ACT[(size_t)(row0 + rloc) * II + n0 + wn * 32 + nn * 16 + fr] = f2bf(s * u * w);
      }
    }
}

// ===================== GEMM2: D[row][h] = ACT @ Wd =====================
// Tile 128(M) x 128(N), BK=64, 4 waves 2x2 (each 64M x 64N). Same B scheme.
__global__ __launch_bounds__(256) void gemm2_kernel(
    const u16* __restrict__ ACT, const float* __restrict__ wd,
    const int* __restrict__ tile_e, const int* __restrict__ tile_r,
    const int* __restrict__ ntiles, u16* __restrict__ D) {
  const int tileid = blockIdx.y;
  if (tileid >= *ntiles) return;
  const int e = tile_e[tileid];
  const int row0 = tile_r[tileid];
  const int n0 = blockIdx.x * 128;

  __shared__ __align__(16) u16 As[2][128 * 64];       // 32 KB
  __shared__ __align__(16) u32 Bs[2][128 * 32];       // 32 KB [buf][n*32+kp]

  const int tid = threadIdx.x;
  const int lane = tid & 63;
  const int wid = tid >> 6;
  const int wm = wid >> 1, wn = wid & 1;
  const int fr = lane & 15, fq = lane >> 4;

  const int lrow = lane >> 3;
  const int sc8 = ((lane & 7) ^ lrow) * 8;

  const u16* gA[4];
#pragma unroll
  for (int j = 0; j < 4; j++)
    gA[j] = ACT + (size_t)(row0 + j * 32 + wid * 8 + lrow) * II + sc8;

  const int n4 = fr * 4;
  const int kpl = wid * 8 + fq;
  const float* gB = wd + (size_t)e * II * HH + n0 + n4;

  f32x4 acc[4][4];
  const f32x4 vz = {0.f, 0.f, 0.f, 0.f};
#pragma unroll
  for (int m = 0; m < 4; m++)
#pragma unroll
    for (int n = 0; n < 4; n++) acc[m][n] = vz;

  f32x4 bl[2][2], bh[2][2];    // [nhalf][round]

#define G2_LOADB(K0)                                                      \
  _Pragma("unroll")                                                       \
  for (int h = 0; h < 2; h++)                                             \
    _Pragma("unroll")                                                     \
    for (int r = 0; r < 2; r++) {                                         \
      const float* p = gB + (size_t)((K0) + 2 * (kpl + r * 4)) * HH + h * 64; \
      bl[h][r] = *(const f32x4*)p;                                        \
      bh[h][r] = *(const f32x4*)(p + HH);                                 \
    }

#define G2_WRITEB(BP)                                                     \
  _Pragma("unroll")                                                       \
  for (int h = 0; h < 2; h++)                                             \
    _Pragma("unroll")                                                     \
    for (int r = 0; r < 2; r++)                                           \
      _Pragma("unroll")                                                   \
      for (int i = 0; i < 4; i++) {                                       \
        const int n = h * 64 + n4 + i;                                    \
        const u32 pk = (u32)f2bf_hw(bl[h][r][i]) |                        \
                       ((u32)f2bf_hw(bh[h][r][i]) << 16);                 \
        (BP)[n * 32 + (((wid * 2 + r) ^ ((n >> 1) & 7)) * 4 | fq)] = pk;  \
      }

#define G2_STAGEA(DST, K0)                                                \
  _Pragma("unroll")                                                       \
  for (int j = 0; j < 4; j++) gld16(gA[j] + (K0), (DST) + (j * 4 + wid) * 512);

#define G2_COMPUTE(ASRC, BP)                                              \
  _Pragma("unroll")                                                       \
  for (int ks = 0; ks < 2; ks++) {                                        \
    short8 af[4];                                                         \
    _Pragma("unroll")                                                     \
    for (int m = 0; m < 4; m++) {                                         \
      const int rr = wm * 64 + m * 16 + fr;                               \
      af[m] = *(const short8*)&(ASRC)[rr * 64 + (((ks * 4 + fq) ^ (rr & 7)) * 8)]; \
    }                                                                     \
    _Pragma("unroll")                                                     \
    for (int nn = 0; nn < 4; nn++) {                                      \
      const int n = wn * 64 + nn * 16 + fr;                               \
      const short8 bb = *(const short8*)&(BP)[n * 32 + (((ks * 4 + fq) ^ ((n >> 1) & 7)) * 4)]; \
      _Pragma("unroll")                                                   \
      for (int m = 0; m < 4; m++)                                         \
        acc[m][nn] = __builtin_amdgcn_mfma_f32_16x16x32_bf16(af[m], bb, acc[m][nn], 0, 0, 0); \
    }                                                                     \
  }

  u16* Acur = &As[0][0]; u16* Anxt = &As[1][0];
  u32* Bcur = &Bs[0][0]; u32* Bnxt = &Bs[1][0];

  G2_LOADB(0)
  G2_STAGEA(Acur, 0)
  G2_WRITEB(Bcur)
  __syncthreads();

  for (int t = 0; t < 8; t++) {
    if (t < 7) {
      G2_LOADB((t + 1) * 64)
      G2_STAGEA(Anxt, (t + 1) * 64)
    }
    G2_COMPUTE(Acur, Bcur)
    if (t < 7) G2_WRITEB(Bnxt)
    __syncthreads();
    u16* ta = Acur; Acur = Anxt; Anxt = ta;
    u32* tb = Bcur; Bcur = Bnxt; Bnxt = tb;
  }

#pragma unroll
  for (int m = 0; m < 4; m++)
#pragma unroll
    for (int jj = 0; jj < 4; jj++) {
      const int rloc = wm * 64 + m * 16 + fq * 4 + jj;
      u16* dp = D + (size_t)(row0 + rloc) * HH + n0 + wn * 64 + fr;
#pragma unroll
      for (int nn = 0; nn < 4; nn++)
        dp[nn * 16] = f2bf(acc[m][nn][jj]);
    }
}

// ---------------- combine: out[t][h] = sum over t's valid pairs of D[row][h] ----------------
__global__ __launch_bounds__(256) void combine_kernel(
    const u16* __restrict__ D, const int* __restrict__ rowof,
    float* __restrict__ out) {
  const int t = blockIdx.x;
  const int h = threadIdx.x * 4;
  const int4 r4 = ((const int4*)rowof)[t];
  float a0 = 0.f, a1 = 0.f, a2 = 0.f, a3 = 0.f;
#define ACCUM(R)                                                     \
  if ((R) >= 0) {                                                    \
    u16x4 d = *(const u16x4*)(D + (size_t)(R) * HH + h);             \
    a0 += bf2f(d[0]); a1 += bf2f(d[1]); a2 += bf2f(d[2]); a3 += bf2f(d[3]); \
  }
  ACCUM(r4.x) ACCUM(r4.y) ACCUM(r4.z) ACCUM(r4.w)
#undef ACCUM
  float4 o = { a0, a1, a2, a3 };
  *(float4*)(out + (size_t)t * HH + h) = o;
}

// ---------------- launch ----------------
extern "C" void kernel_launch(void* const* d_in, const int* in_sizes, int n_in,
                              void* d_out, int out_size, void* d_ws, size_t ws_size,
                              hipStream_t stream) {
  const float* x = (const float*)d_in[0];
  const int* tidx = (const int*)d_in[1];
  const float* tw = (const float*)d_in[2];
  const float* wg = (const float*)d_in[3];
  const float* wu = (const float*)d_in[4];
  const float* wd = (const float*)d_in[5];
  float* out = (float*)d_out;

  char* ws = (char*)d_ws;
  int* ntiles = (int*)(ws + 0);
  int* tile_e = (int*)(ws + 1024);
  int* tile_r = (int*)(ws + 2048);
  int* perm = (int*)(ws + 4096);                 // 12288 ints
  float* wt = (float*)(ws + 53248);              // 12288 floats
  int* rowof = (int*)(ws + 102400);              // 8192 ints
  u16* xb = (u16*)(ws + 262144);                 // [2048][1024] bf16, 4 MB
  u16* D = (u16*)(ws + 4456448);                 // [MAXROWS][H] bf16, 25.2 MB
  u16* ACT = (u16*)(ws + 54788096);              // [MAXROWS][I] bf16, 12.58 MB

  prep_small<<<129, 1024, 0, stream>>>(x, tidx, tw, xb, perm, wt, rowof,
                                       tile_e, tile_r, ntiles);
  gemm1_kernel<<<dim3(II / 64, 80), 256, 0, stream>>>(xb, wg, wu, perm, wt,
                                                      tile_e, tile_r, ntiles, ACT);
  gemm2_kernel<<<dim3(HH / 128, 80), 256, 0, stream>>>(ACT, wd,
                                                       tile_e, tile_r, ntiles, D);
  combine_kernel<<<TT, 256, 0, stream>>>(D, rowof, out);
}